// Round 11
// baseline (109.745 us; speedup 1.0000x reference)
//
#include <hip/hip_runtime.h>

#define BB 4
#define NN 16384
#define MM 8192      // N/2
#define FD 64
#define CHUNK 256    // candidates staged per LDS tile (1 per thread)
#define QPT 2        // queries per thread (register-blocked)
#define TPB 256      // threads per block
#define QPB (TPB * QPT)   // 512 queries per block
#define NBOUND 512   // candidates scanned by the bound pass

// d_out float offsets (outputs concatenated flat in return order)
#define OUT0 0              // valid_pc   (4,8192,3)  = 98304
#define OUT1 98304          // valid_feats(4,8192,64) = 2097152
#define OUT2 2195456        // n_idx      (4,8192)    = 32768
#define OUT3 2228224        // rnds       (1,16384)   = 16384

#define CAND_BYTES  ((size_t)BB * MM * 16)   // 512 KB: float4 (2x,2y,2z,p2)
#define BOUND_BYTES ((size_t)BB * MM * 4)    // 128 KB: f32 bound per query

struct Partial { double m1, m2; };  // 16B packed keys

// Reference fp32 chain (verified absmax=0): rounded squares, sequential adds.
__device__ __forceinline__ float sumsq3_rn(float x, float y, float z) {
  return __fadd_rn(__fadd_rn(__fmul_rn(x, x), __fmul_rn(y, y)), __fmul_rn(z, z));
}
// Bit-exact d2 from pre-doubled candidate (2x,2y,2z,p2) — HW-verified r7/r10.
__device__ __forceinline__ float dist2_rn(float qx, float qy, float qz, float q2,
                                          float4 t) {
  float cross2 = __fmaf_rn(qz, t.z, __fmaf_rn(qy, t.y, __fmul_rn(qx, t.x)));
  return __fadd_rn(__fsub_rn(q2, cross2), t.w);
}

// Packed key: hi word = f32 bits of d2, lo word = candidate index.
// f64 ordering == (f32 d2 compare, then lower-index-first) for all finite d2.
__device__ __forceinline__ double mkkey(float d2, int k) {
  return __hiloint2double(__float_as_int(d2), k);
}
#define KEY_INIT __hiloint2double(0x7F800000, 0x7FFFFFFF)   // +inf d2 sentinel

__global__ __launch_bounds__(256) void gather_kernel(
    const float* __restrict__ pc, const float* __restrict__ feats,
    const int* __restrict__ perm, float* __restrict__ out,
    float4* __restrict__ cand) {
  int idx = blockIdx.x * 256 + threadIdx.x;
  const int F4_TOT = BB * MM * FD / 4;   // 524288 float4 of feats
  const int PTS    = BB * MM;            // 32768 valid points (pc)
  if (idx < F4_TOT) {
    int f4 = idx & 15;                   // float4 within row
    int r  = (idx >> 4) & (MM - 1);
    int b  = idx >> 17;                  // / (MM*16)
    int vi = perm[r];
    const float4* src = (const float4*)(feats + ((b * NN + vi) << 6));
    float4* dst = (float4*)(out + OUT1) + idx;
    *dst = src[f4];
  } else if (idx < F4_TOT + PTS) {
    int k = idx - F4_TOT;                // k == b*MM + r == cand index
    int r = k & (MM - 1);
    int b = k >> 13;
    int vi = perm[r];
    const float* src = pc + (b * NN + vi) * 3;
    float px = src[0], py = src[1], pz = src[2];
    float* dst = out + OUT0 + k * 3;
    dst[0] = px; dst[1] = py; dst[2] = pz;
    cand[k] = make_float4(px + px, py + py, pz + pz, sumsq3_rn(px, py, pz));
  } else if (idx < F4_TOT + PTS + NN) {
    int k = idx - F4_TOT - PTS;
    out[OUT3 + k] = (float)perm[k];
  }
}

// Stage 1: per query, 2nd-min rounded-d2 over candidates [0,NBOUND) — a true
// upper bound on the final m2 value in the same rounded metric (f32 only,
// med3/min recurrence HW-verified r7). Wave reads are broadcast (same addr).
__global__ __launch_bounds__(256) void bound_kernel(
    const float* __restrict__ pc, const int* __restrict__ perm,
    const float4* __restrict__ cand, float* __restrict__ bound2) {
  #pragma clang fp contract(off)
  int q = blockIdx.x * 256 + threadIdx.x;   // 0..B*M-1
  int b = q >> 13;
  int j = q & (MM - 1);
  int qi = perm[MM + j];
  const float* qp = pc + (b * NN + qi) * 3;
  float qx = qp[0], qy = qp[1], qz = qp[2];
  float q2 = sumsq3_rn(qx, qy, qz);
  float m1 = 3.4e38f, m2 = 3.4e38f;
  const float4* cb = cand + b * MM;
  #pragma unroll 8
  for (int k = 0; k < NBOUND; ++k) {
    float d2 = dist2_rn(qx, qy, qz, q2, cb[k]);
    m2 = __builtin_amdgcn_fmed3f(d2, m1, m2);
    m1 = fminf(d2, m1);
  }
  bound2[q] = m2;
}

// Main: QPB queries x span candidates via LDS broadcast; f64 packed-key top-2
// executed only under the f32 prefilter (d2 <= bound2). Lanes entering via the
// OR may insert keys with d2 > bound2 — harmless (merge-min can't promote them
// past the final top-2, whose values are <= bound2). Lanes skipped have
// key > final m2key, also a no-op. '<=' keeps bit-equal ties (index tiebreak).
__global__ __launch_bounds__(256) void knn_kernel(
    const float* __restrict__ pc, const int* __restrict__ perm,
    const float4* __restrict__ cand, const float* __restrict__ bound2,
    Partial* __restrict__ part, float* __restrict__ out, int nchunk) {
  #pragma clang fp contract(off)
  int blk = blockIdx.x;
  int c  = blk % nchunk;          // chunk id
  int qb = blk / nchunk;          // query-block id
  int q0 = qb * QPB + threadIdx.x;   // first of QPT strided queries
  int b  = qb >> 4;               // blockIdx-only -> uniform

  float qx[QPT], qy[QPT], qz[QPT], q2[QPT], bf[QPT];
  double m1[QPT], m2[QPT];
  #pragma unroll
  for (int s = 0; s < QPT; ++s) {
    int q = q0 + s * TPB;
    int j = q & (MM - 1);
    int qi = perm[MM + j];
    const float* qp = pc + (b * NN + qi) * 3;
    qx[s] = qp[0]; qy[s] = qp[1]; qz[s] = qp[2];
    q2[s] = sumsq3_rn(qx[s], qy[s], qz[s]);
    bf[s] = bound2[q];
    m1[s] = KEY_INIT; m2[s] = KEY_INIT;
  }

  __shared__ float4 tile[CHUNK];   // (2x, 2y, 2z, p2)  4 KB

  int span = MM / nchunk;
  int begin = c * span, end = begin + span;

  for (int t0 = begin; t0 < end; t0 += CHUNK) {
    __syncthreads();
    tile[threadIdx.x] = cand[b * MM + t0 + threadIdx.x];  // coalesced, L2-hot
    __syncthreads();
    #pragma unroll 4
    for (int k = 0; k < CHUNK; ++k) {
      float4 t = tile[k];
      int idx = t0 + k;
      float d2a = dist2_rn(qx[0], qy[0], qz[0], q2[0], t);
      float d2b = dist2_rn(qx[1], qy[1], qz[1], q2[1], t);
      if (__builtin_expect((d2a <= bf[0]) | (d2b <= bf[1]), 0)) {
        double ka = mkkey(d2a, idx);
        double kb = mkkey(d2b, idx);
        m2[0] = fmin(fmax(ka, m1[0]), m2[0]);
        m1[0] = fmin(ka, m1[0]);
        m2[1] = fmin(fmax(kb, m1[1]), m2[1]);
        m1[1] = fmin(kb, m1[1]);
      }
    }
  }

  #pragma unroll
  for (int s = 0; s < QPT; ++s) {
    int q = q0 + s * TPB;
    if (part != nullptr) {
      Partial pr; pr.m1 = m1[s]; pr.m2 = m2[s];
      part[q * nchunk + c] = pr;
    } else {
      out[OUT2 + q] = (float)__double2loint(m2[s]);
    }
  }
}

__global__ __launch_bounds__(256) void knn_merge_kernel(
    const Partial* __restrict__ part, float* __restrict__ out, int nchunk) {
  int q = blockIdx.x * 256 + threadIdx.x;   // 0..B*M-1
  double m1 = KEY_INIT, m2 = KEY_INIT;
  for (int c = 0; c < nchunk; ++c) {
    Partial p = part[q * nchunk + c];
    // key insertion is order-independent (keys are totally ordered)
    m2 = fmin(fmax(p.m1, m1), m2);
    m1 = fmin(p.m1, m1);
    m2 = fmin(fmax(p.m2, m1), m2);
    m1 = fmin(p.m2, m1);
  }
  out[OUT2 + q] = (float)__double2loint(m2);
}

extern "C" void kernel_launch(void* const* d_in, const int* in_sizes, int n_in,
                              void* d_out, int out_size, void* d_ws, size_t ws_size,
                              hipStream_t stream) {
  const float* pc    = (const float*)d_in[0];
  const float* feats = (const float*)d_in[1];
  const int*   perm  = (const int*)d_in[2];
  float* out = (float*)d_out;

  float4* cand   = (float4*)d_ws;                            // 512 KB
  float*  bound2 = (float*)((char*)d_ws + CAND_BYTES);       // 128 KB
  char*   rest   = (char*)d_ws + CAND_BYTES + BOUND_BYTES;
  size_t  used   = CAND_BYTES + BOUND_BYTES;
  size_t  avail  = ws_size > used ? ws_size - used : 0;

  // Gather (+ cand prep): 2240 blocks
  gather_kernel<<<2240, 256, 0, stream>>>(pc, feats, perm, out, cand);

  // Stage 1: f32 upper bound on final m2 per query (scans cand[0:512))
  bound_kernel<<<BB * MM / 256, 256, 0, stream>>>(pc, perm, cand, bound2);

  // Largest chunk split whose partials fit after cand+bound.
  // qblocks = 64 -> nchunk=32 gives 2048 blocks (8/CU) — best measured shape.
  int nchunk = 1;
  if      (avail >= (size_t)BB * MM * 32 * sizeof(Partial)) nchunk = 32;  // 16.8 MB
  else if (avail >= (size_t)BB * MM * 16 * sizeof(Partial)) nchunk = 16;
  else if (avail >= (size_t)BB * MM * 8  * sizeof(Partial)) nchunk = 8;
  else if (avail >= (size_t)BB * MM * 4  * sizeof(Partial)) nchunk = 4;
  else if (avail >= (size_t)BB * MM * 2  * sizeof(Partial)) nchunk = 2;

  int qblocks = BB * MM / QPB;   // 64
  if (nchunk > 1) {
    Partial* part = (Partial*)rest;
    knn_kernel<<<qblocks * nchunk, TPB, 0, stream>>>(pc, perm, cand, bound2,
                                                     part, out, nchunk);
    knn_merge_kernel<<<BB * MM / 256, 256, 0, stream>>>(part, out, nchunk);
  } else {
    knn_kernel<<<qblocks, TPB, 0, stream>>>(pc, perm, cand, bound2,
                                            nullptr, out, 1);
  }
}